// Round 11
// baseline (1285.409 us; speedup 1.0000x reference)
//
#include <hip/hip_runtime.h>

#define N_NODES 50000
#define N_EDGES 800000
#define DIM 128
#define NEG_SLOPE 0.01f
#define CAP 32           // bucket capacity
#define OVF_MAX 4096     // overflow list capacity (expected usage: tens)

// ---- dst binning (8 bins ~ 8 XCDs) ----
#define NBIN 8
#define BINCAP 131072    // per-bin record capacity (mean ~100K, sd ~320)

// ---- out-degree histogram partitioning ----
#define NR 4             // node ranges
#define RNODES 12512     // nodes per range (4*12512 = 50048 >= 50000), LDS 50 KB
#define SLICES 64        // edge slices per range
#define ESLICE (N_EDGES / SLICES)   // 12500 edges per slice

// ---- bf16 pack/unpack (RNE) ----
__device__ inline unsigned f2b_rne2(float a, float b) {
    unsigned ua = __float_as_uint(a), ub = __float_as_uint(b);
    ua = (ua + 0x7fffu + ((ua >> 16) & 1u)) >> 16;
    ub = (ub + 0x7fffu + ((ub >> 16) & 1u)) >> 16;
    return ua | (ub << 16);
}
__device__ inline float b2f_lo(unsigned u) { return __uint_as_float(u << 16); }
__device__ inline float b2f_hi(unsigned u) { return __uint_as_float(u & 0xffff0000u); }

// bin mapping: ~uniform 8 ranges over 50048 nodes (335/2^21 ~= 8/50048)
__device__ inline int dst_bin(int d) { return (int)(((unsigned)d * 335u) >> 21); }

// ---------------- phase 1: pack & bin edges by dst range ----------------
// per-wave ballot aggregation: one cursor atomic per (wave, bin); records of the
// same bin within a wave write consecutive slots (coalesced runs).
__global__ void k_bin(const int* __restrict__ src, const int* __restrict__ dst,
                      int* __restrict__ binCnt, unsigned* __restrict__ binned,
                      int* __restrict__ icnt, unsigned short* __restrict__ eidx,
                      int* __restrict__ ovf_cnt, int2* __restrict__ ovf, int ne) {
    int e = blockIdx.x * blockDim.x + threadIdx.x;
    if (e >= ne) return;
    int s = src[e], d = dst[e];
    unsigned rec = ((unsigned)d << 16) | (unsigned)s;
    int b = dst_bin(d);
    int lane = threadIdx.x & 63;
    #pragma unroll
    for (int bb = 0; bb < NBIN; ++bb) {
        unsigned long long m = __ballot(b == bb);
        if (m) {
            int leader = __ffsll(m) - 1;
            int base = 0;
            if (lane == leader) base = atomicAdd(&binCnt[bb], __popcll(m));
            base = __shfl(base, leader);
            if (b == bb) {
                int rank = __popcll(m & ((1ull << lane) - 1ull));
                int p = base + rank;
                if (p < BINCAP) {
                    binned[bb * BINCAP + p] = rec;
                } else {                       // ~impossible fallback: direct fill
                    int q0 = atomicAdd(&icnt[d], 1);
                    if (q0 < CAP) eidx[d * CAP + q0] = (unsigned short)s;
                    else { int o = atomicAdd(ovf_cnt, 1);
                           if (o < OVF_MAX) ovf[o] = make_int2(d, s); }
                }
            }
        }
    }
}

// ---------------- phase 2: per-bin fill (XCD-affine blocks) ----------------
// blocks with blockIdx%NBIN==b process bin b -> each bin's eidx region (~800KB)
// is dirtied from one XCD's L2 -> partial-line multi-XCD writeback amp avoided.
__global__ void k_fill2(const int* __restrict__ binCnt, const unsigned* __restrict__ binned,
                        int* __restrict__ icnt, unsigned short* __restrict__ eidx,
                        int* __restrict__ ovf_cnt, int2* __restrict__ ovf) {
    int b = blockIdx.x & (NBIN - 1);
    int sub = blockIdx.x >> 3;             // 0..31
    int cnt = min(binCnt[b], BINCAP);
    const unsigned* rb = binned + b * BINCAP;
    for (int i = sub * 256 + threadIdx.x; i < cnt; i += 32 * 256) {
        unsigned rec = rb[i];
        int d = rec >> 16, s = rec & 0xffffu;
        int p = atomicAdd(&icnt[d], 1);
        if (p < CAP) eidx[d * CAP + p] = (unsigned short)s;
        else { int o = atomicAdd(ovf_cnt, 1);
               if (o < OVF_MAX) ovf[o] = make_int2(d, s); }
    }
}

// ---------------- out-degree histogram: LDS-privatized, range x slice ----------------
__global__ __launch_bounds__(256) void k_hist(const int* __restrict__ src,
                                              int* __restrict__ partial) {
    __shared__ int bins[RNODES];           // 50 KB
    int range = blockIdx.x / SLICES;
    int slice = blockIdx.x % SLICES;
    int tid = threadIdx.x;
    for (int j = tid; j < RNODES; j += 256) bins[j] = 0;
    __syncthreads();
    int base_node = range * RNODES;
    const int4* src4 = (const int4*)(src + slice * ESLICE);
    for (int t = tid; t < ESLICE / 4; t += 256) {
        int4 v = src4[t];
        unsigned u0 = (unsigned)(v.x - base_node);
        unsigned u1 = (unsigned)(v.y - base_node);
        unsigned u2 = (unsigned)(v.z - base_node);
        unsigned u3 = (unsigned)(v.w - base_node);
        if (u0 < RNODES) atomicAdd(&bins[u0], 1);
        if (u1 < RNODES) atomicAdd(&bins[u1], 1);
        if (u2 < RNODES) atomicAdd(&bins[u2], 1);
        if (u3 < RNODES) atomicAdd(&bins[u3], 1);
    }
    __syncthreads();
    int* outp = partial + (size_t)blockIdx.x * RNODES;
    for (int j = tid; j < RNODES; j += 256) outp[j] = bins[j];
}

// ---------------- per-node prep (sums out-degree partials inline) ----------------
__global__ void k_prep(const float* __restrict__ weight, const int* __restrict__ sig,
                       const float* __restrict__ emb,
                       const int* __restrict__ partial, const int* __restrict__ icnt,
                       float* __restrict__ oinv, float* __restrict__ iinv,
                       float* __restrict__ feats3, int n) {
    int i = blockIdx.x * blockDim.x + threadIdx.x;
    if (i >= n) return;
    int range = i / RNODES, off = i % RNODES;
    const int* p = partial + ((size_t)range * SLICES) * RNODES + off;
    int od = 0;
    #pragma unroll 8
    for (int s = 0; s < SLICES; ++s) od += p[(size_t)s * RNODES];
    float odf = (float)max(od, 1);
    float idf = (float)max(icnt[i], 1);
    float oi = 1.0f / sqrtf(odf);
    oinv[i] = oi;
    iinv[i] = 1.0f / sqrtf(idf);
    int sg = sig[i];
    feats3[i * 3 + 0] = weight[i] * oi;
    feats3[i * 3 + 1] = emb[sg * 2 + 0] * oi;
    feats3[i * 3 + 2] = emb[sg * 2 + 1] * oi;
}

// ---------------- layer-1 overflow patch: agg3ovf[dst] += feats3[src] ----------------
__global__ void k_ovf3(const int* __restrict__ ovf_cnt, const int2* __restrict__ ovf,
                       const float* __restrict__ feats3, float* __restrict__ agg3ovf) {
    int t = blockIdx.x * blockDim.x + threadIdx.x;
    int cnt = min(*ovf_cnt, OVF_MAX);
    if (t >= cnt) return;
    int2 e = ovf[t];                           // (dst, src)
    atomicAdd(&agg3ovf[e.x * 3 + 0], feats3[e.y * 3 + 0]);
    atomicAdd(&agg3ovf[e.x * 3 + 1], feats3[e.y * 3 + 1]);
    atomicAdd(&agg3ovf[e.x * 3 + 2], feats3[e.y * 3 + 2]);
}

// ---------------- fused layer-1: agg3 gather + (.@W0+b0) + lrelu + bf16 pack ----------------
__global__ void k_aggl1(const int* __restrict__ icnt, const unsigned short* __restrict__ eidx,
                        const float* __restrict__ feats3, const float* __restrict__ agg3ovf,
                        const float* __restrict__ iinv, const float* __restrict__ oinv,
                        const float* __restrict__ W0, const float* __restrict__ b0,
                        unsigned* __restrict__ hs, int n) {
    int t = blockIdx.x * blockDim.x + threadIdx.x;
    int i = t >> 5;
    if (i >= n) return;
    int q = t & 31;
    int deg = min(icnt[i], CAP);
    const unsigned short* row = eidx + i * CAP;
    float a0 = 0.f, a1 = 0.f, a2 = 0.f;
    for (int k = q; k < deg; k += 32) {
        int s = row[k];
        a0 += feats3[s * 3 + 0];
        a1 += feats3[s * 3 + 1];
        a2 += feats3[s * 3 + 2];
    }
    #pragma unroll
    for (int m = 1; m <= 16; m <<= 1) {
        a0 += __shfl_xor(a0, m);
        a1 += __shfl_xor(a1, m);
        a2 += __shfl_xor(a2, m);
    }
    a0 += agg3ovf[i * 3 + 0];
    a1 += agg3ovf[i * 3 + 1];
    a2 += agg3ovf[i * 3 + 2];
    float ii = iinv[i], oi = oinv[i];
    a0 *= ii; a1 *= ii; a2 *= ii;
    int j0 = q * 4;
    float4 w0r = *(const float4*)&W0[0 * DIM + j0];
    float4 w1r = *(const float4*)&W0[1 * DIM + j0];
    float4 w2r = *(const float4*)&W0[2 * DIM + j0];
    float4 bb  = *(const float4*)&b0[j0];
    float v0 = a0 * w0r.x + a1 * w1r.x + a2 * w2r.x + bb.x;
    float v1 = a0 * w0r.y + a1 * w1r.y + a2 * w2r.y + bb.y;
    float v2 = a0 * w0r.z + a1 * w1r.z + a2 * w2r.z + bb.z;
    float v3 = a0 * w0r.w + a1 * w1r.w + a2 * w2r.w + bb.w;
    v0 = v0 > 0.f ? v0 : NEG_SLOPE * v0;
    v1 = v1 > 0.f ? v1 : NEG_SLOPE * v1;
    v2 = v2 > 0.f ? v2 : NEG_SLOPE * v2;
    v3 = v3 > 0.f ? v3 : NEG_SLOPE * v3;
    ((uint2*)hs)[i * 32 + q] = make_uint2(f2b_rne2(v0 * oi, v1 * oi),
                                          f2b_rne2(v2 * oi, v3 * oi));
}

// ---------------- layer-2 aggregation: bucket gather, 32 threads/node ----------------
__global__ void k_gather128(const int* __restrict__ icnt, const unsigned short* __restrict__ eidx,
                            const unsigned* __restrict__ hs, float* __restrict__ out, int n) {
    int t = blockIdx.x * blockDim.x + threadIdx.x;
    int i = t >> 5;
    if (i >= n) return;
    int q = t & 31;
    int deg = min(icnt[i], CAP);
    const unsigned short* row = eidx + i * CAP;
    const uint2* hs2 = (const uint2*)hs;
    float a0 = 0.f, a1 = 0.f, a2 = 0.f, a3 = 0.f;
    int k = 0;
    for (; k + 2 <= deg; k += 2) {
        int s0 = row[k], s1 = row[k + 1];
        uint2 u0 = hs2[s0 * 32 + q];
        uint2 u1 = hs2[s1 * 32 + q];
        a0 += b2f_lo(u0.x) + b2f_lo(u1.x);
        a1 += b2f_hi(u0.x) + b2f_hi(u1.x);
        a2 += b2f_lo(u0.y) + b2f_lo(u1.y);
        a3 += b2f_hi(u0.y) + b2f_hi(u1.y);
    }
    if (k < deg) {
        int s = row[k];
        uint2 u = hs2[s * 32 + q];
        a0 += b2f_lo(u.x); a1 += b2f_hi(u.x);
        a2 += b2f_lo(u.y); a3 += b2f_hi(u.y);
    }
    ((float4*)out)[i * 32 + q] = make_float4(a0, a1, a2, a3);
}

// ---------------- layer-2 overflow edges: atomic add into out ----------------
__global__ void k_overflow(const int* __restrict__ ovf_cnt, const int2* __restrict__ ovf,
                           const unsigned* __restrict__ hs, float* __restrict__ out) {
    int g = blockIdx.x * blockDim.x + threadIdx.x;
    int entry = g >> 5, q = g & 31;
    int cnt = min(*ovf_cnt, OVF_MAX);
    if (entry >= cnt) return;
    int2 e = ovf[entry];                       // (dst, src)
    uint2 u = ((const uint2*)hs)[e.y * 32 + q];
    float* o = out + (size_t)e.x * DIM + q * 4;
    atomicAdd(o + 0, b2f_lo(u.x));
    atomicAdd(o + 1, b2f_hi(u.x));
    atomicAdd(o + 2, b2f_lo(u.y));
    atomicAdd(o + 3, b2f_hi(u.y));
}

// ---------------- final: out = (out * iinv) @ W1 + b1 ----------------
#define FB_NODES 128
__global__ __launch_bounds__(256) void k_final(const float* __restrict__ iinv,
                                               const float* __restrict__ W1,
                                               const float* __restrict__ b1,
                                               float* __restrict__ out, int n) {
    __shared__ float sW[DIM * DIM];        // 64 KB
    int tid = threadIdx.x;
    for (int idx = tid; idx < DIM * DIM / 4; idx += 256)
        ((float4*)sW)[idx] = ((const float4*)W1)[idx];

    int cg = tid & 15, ng = tid >> 4;
    int col0 = cg * 8;
    int row0 = blockIdx.x * FB_NODES + ng * 8;

    float acc[8][8];
    #pragma unroll
    for (int i = 0; i < 8; ++i)
        #pragma unroll
        for (int j = 0; j < 8; ++j) acc[i][j] = 0.f;

    __syncthreads();

    const float4* outf4 = (const float4*)out;
    for (int k4 = 0; k4 < 32; ++k4) {
        float4 a[8];
        #pragma unroll
        for (int i = 0; i < 8; ++i) {
            int r = min(row0 + i, n - 1);          // clamped read; store is guarded
            a[i] = outf4[(size_t)r * 32 + k4];
        }
        #pragma unroll
        for (int kk = 0; kk < 4; ++kk) {
            float4 w0 = *(const float4*)&sW[(k4 * 4 + kk) * DIM + col0];
            float4 w1v = *(const float4*)&sW[(k4 * 4 + kk) * DIM + col0 + 4];
            #pragma unroll
            for (int i = 0; i < 8; ++i) {
                float av = (kk == 0) ? a[i].x : (kk == 1) ? a[i].y : (kk == 2) ? a[i].z : a[i].w;
                acc[i][0] += av * w0.x;  acc[i][1] += av * w0.y;
                acc[i][2] += av * w0.z;  acc[i][3] += av * w0.w;
                acc[i][4] += av * w1v.x; acc[i][5] += av * w1v.y;
                acc[i][6] += av * w1v.z; acc[i][7] += av * w1v.w;
            }
        }
    }

    __syncthreads();                       // all in-place reads done before writes

    #pragma unroll
    for (int i = 0; i < 8; ++i) {
        int r = row0 + i;
        if (r < n) {
            float ii = iinv[r];
            float4 bb0 = *(const float4*)&b1[col0];
            float4 bb1 = *(const float4*)&b1[col0 + 4];
            float4 o0, o1;
            o0.x = acc[i][0] * ii + bb0.x; o0.y = acc[i][1] * ii + bb0.y;
            o0.z = acc[i][2] * ii + bb0.z; o0.w = acc[i][3] * ii + bb0.w;
            o1.x = acc[i][4] * ii + bb1.x; o1.y = acc[i][5] * ii + bb1.y;
            o1.z = acc[i][6] * ii + bb1.z; o1.w = acc[i][7] * ii + bb1.w;
            ((float4*)out)[(size_t)r * 32 + (col0 >> 2)] = o0;
            ((float4*)out)[(size_t)r * 32 + (col0 >> 2) + 1] = o1;
        }
    }
}

// ---------------- launch ----------------
extern "C" void kernel_launch(void* const* d_in, const int* in_sizes, int n_in,
                              void* d_out, int out_size, void* d_ws, size_t ws_size,
                              hipStream_t stream) {
    const int*   src  = (const int*)d_in[0];
    const int*   dst  = (const int*)d_in[1];
    const float* weight = (const float*)d_in[2];
    const int*   sig  = (const int*)d_in[3];
    const float* emb  = (const float*)d_in[4];
    const float* W0   = (const float*)d_in[5];
    const float* b0   = (const float*)d_in[6];
    const float* W1   = (const float*)d_in[7];
    const float* b1   = (const float*)d_in[8];
    float* out = (float*)d_out;

    // ---- workspace layout (4B words); zeroed buffers first ----
    int*   icnt    = (int*)d_ws;                          // @0        50000 (memset)
    int*   ovf_cnt = icnt + N_NODES;                      // @50000    8     (memset)
    int*   binCnt  = ovf_cnt + 8;                         // @50008    8     (memset)
    float* agg3ovf = (float*)(binCnt + 8);                // @50016    150000 (memset)
    int2*  ovf     = (int2*)(agg3ovf + 3 * N_NODES);      // @200016   4096 int2 (byte %8==0)
    float* oinv    = (float*)(ovf + OVF_MAX);             // @208208   50000
    float* iinv    = oinv + N_NODES;                      // @258208   50000
    float* feats3  = iinv + N_NODES;                      // @308208   150000
    int*   partial = (int*)(feats3 + 3 * N_NODES);        // @458208   3203072
    unsigned* binned = (unsigned*)(partial + (size_t)NR * SLICES * RNODES); // 8*131072
    unsigned short* eidx = (unsigned short*)(binned + (size_t)NBIN * BINCAP);
    unsigned* hs   = (unsigned*)(eidx + (size_t)N_NODES * CAP);     // (byte %8==0)

    hipMemsetAsync(d_ws, 0, (size_t)(N_NODES + 16 + 3 * N_NODES) * 4, stream);

    k_bin<<<(N_EDGES + 255) / 256, 256, 0, stream>>>(src, dst, binCnt, binned,
                                                     icnt, eidx, ovf_cnt, ovf, N_EDGES);
    k_fill2<<<32 * NBIN, 256, 0, stream>>>(binCnt, binned, icnt, eidx, ovf_cnt, ovf);
    k_hist<<<NR * SLICES, 256, 0, stream>>>(src, partial);
    k_prep<<<(N_NODES + 255) / 256, 256, 0, stream>>>(weight, sig, emb, partial, icnt,
                                                      oinv, iinv, feats3, N_NODES);
    k_ovf3<<<(OVF_MAX + 255) / 256, 256, 0, stream>>>(ovf_cnt, ovf, feats3, agg3ovf);
    k_aggl1<<<(N_NODES * 32 + 255) / 256, 256, 0, stream>>>(icnt, eidx, feats3, agg3ovf,
                                                            iinv, oinv, W0, b0, hs, N_NODES);
    k_gather128<<<((N_NODES * 32) + 255) / 256, 256, 0, stream>>>(icnt, eidx, hs, out, N_NODES);
    k_overflow<<<(OVF_MAX * 32) / 256, 256, 0, stream>>>(ovf_cnt, ovf, hs, out);
    k_final<<<(N_NODES + FB_NODES - 1) / FB_NODES, 256, 0, stream>>>(iinv, W1, b1, out, N_NODES);
}

// Round 12
// 156.694 us; speedup vs baseline: 8.2033x; 8.2033x over previous
//
#include <hip/hip_runtime.h>

#define N_NODES 50000
#define N_EDGES 800000
#define DIM 128
#define NEG_SLOPE 0.01f
#define CAP 32           // bucket capacity
#define OVF_MAX 4096     // overflow list capacity (expected usage: tens)

// ---- out-degree histogram partitioning ----
#define NR 4             // node ranges
#define RNODES 12512     // nodes per range (4*12512 = 50048 >= 50000), LDS 50 KB
#define SLICES 64        // edge slices per range
#define ESLICE (N_EDGES / SLICES)   // 12500 edges per slice

// ---- bf16 pack/unpack (RNE) ----
__device__ inline unsigned f2b_rne2(float a, float b) {
    unsigned ua = __float_as_uint(a), ub = __float_as_uint(b);
    ua = (ua + 0x7fffu + ((ua >> 16) & 1u)) >> 16;
    ub = (ub + 0x7fffu + ((ub >> 16) & 1u)) >> 16;
    return ua | (ub << 16);
}
__device__ inline float b2f_lo(unsigned u) { return __uint_as_float(u << 16); }
__device__ inline float b2f_hi(unsigned u) { return __uint_as_float(u & 0xffff0000u); }

// ---------------- bucket build: 1 atomic/edge (icnt doubles as cursor) ----------------
__global__ void k_fillbucket(const int* __restrict__ src, const int* __restrict__ dst,
                             int* __restrict__ icnt,
                             unsigned short* __restrict__ eidx,
                             int* __restrict__ ovf_cnt, int2* __restrict__ ovf, int ne2) {
    int t = blockIdx.x * blockDim.x + threadIdx.x;
    if (t >= ne2) return;
    int2 s = ((const int2*)src)[t];
    int2 d = ((const int2*)dst)[t];
    int p0 = atomicAdd(&icnt[d.x], 1);
    if (p0 < CAP) eidx[d.x * CAP + p0] = (unsigned short)s.x;
    else { int o = atomicAdd(ovf_cnt, 1); if (o < OVF_MAX) ovf[o] = make_int2(d.x, s.x); }
    int p1 = atomicAdd(&icnt[d.y], 1);
    if (p1 < CAP) eidx[d.y * CAP + p1] = (unsigned short)s.y;
    else { int o = atomicAdd(ovf_cnt, 1); if (o < OVF_MAX) ovf[o] = make_int2(d.y, s.y); }
}

// ---------------- out-degree histogram: LDS-privatized, range x slice ----------------
__global__ __launch_bounds__(256) void k_hist(const int* __restrict__ src,
                                              int* __restrict__ partial) {
    __shared__ int bins[RNODES];           // 50 KB
    int range = blockIdx.x / SLICES;
    int slice = blockIdx.x % SLICES;
    int tid = threadIdx.x;
    for (int j = tid; j < RNODES; j += 256) bins[j] = 0;
    __syncthreads();
    int base_node = range * RNODES;
    const int4* src4 = (const int4*)(src + slice * ESLICE);
    for (int t = tid; t < ESLICE / 4; t += 256) {
        int4 v = src4[t];
        unsigned u0 = (unsigned)(v.x - base_node);
        unsigned u1 = (unsigned)(v.y - base_node);
        unsigned u2 = (unsigned)(v.z - base_node);
        unsigned u3 = (unsigned)(v.w - base_node);
        if (u0 < RNODES) atomicAdd(&bins[u0], 1);
        if (u1 < RNODES) atomicAdd(&bins[u1], 1);
        if (u2 < RNODES) atomicAdd(&bins[u2], 1);
        if (u3 < RNODES) atomicAdd(&bins[u3], 1);
    }
    __syncthreads();
    int* outp = partial + (size_t)blockIdx.x * RNODES;
    for (int j = tid; j < RNODES; j += 256) outp[j] = bins[j];
}

// ---------------- per-node prep (sums out-degree partials inline) ----------------
__global__ void k_prep(const float* __restrict__ weight, const int* __restrict__ sig,
                       const float* __restrict__ emb,
                       const int* __restrict__ partial, const int* __restrict__ icnt,
                       float* __restrict__ oinv, float* __restrict__ iinv,
                       float* __restrict__ feats3, int n) {
    int i = blockIdx.x * blockDim.x + threadIdx.x;
    if (i >= n) return;
    int range = i / RNODES, off = i % RNODES;
    const int* p = partial + ((size_t)range * SLICES) * RNODES + off;
    int od = 0;
    #pragma unroll 8
    for (int s = 0; s < SLICES; ++s) od += p[(size_t)s * RNODES];
    float odf = (float)max(od, 1);
    float idf = (float)max(icnt[i], 1);
    float oi = 1.0f / sqrtf(odf);
    oinv[i] = oi;
    iinv[i] = 1.0f / sqrtf(idf);
    int sg = sig[i];
    feats3[i * 3 + 0] = weight[i] * oi;
    feats3[i * 3 + 1] = emb[sg * 2 + 0] * oi;
    feats3[i * 3 + 2] = emb[sg * 2 + 1] * oi;
}

// ---------------- layer-1 overflow patch: agg3ovf[dst] += feats3[src] ----------------
__global__ void k_ovf3(const int* __restrict__ ovf_cnt, const int2* __restrict__ ovf,
                       const float* __restrict__ feats3, float* __restrict__ agg3ovf) {
    int t = blockIdx.x * blockDim.x + threadIdx.x;
    int cnt = min(*ovf_cnt, OVF_MAX);
    if (t >= cnt) return;
    int2 e = ovf[t];                           // (dst, src)
    atomicAdd(&agg3ovf[e.x * 3 + 0], feats3[e.y * 3 + 0]);
    atomicAdd(&agg3ovf[e.x * 3 + 1], feats3[e.y * 3 + 1]);
    atomicAdd(&agg3ovf[e.x * 3 + 2], feats3[e.y * 3 + 2]);
}

// ---------------- fused layer-1: agg3 gather + (.@W0+b0) + lrelu + bf16 pack ----------------
__global__ void k_aggl1(const int* __restrict__ icnt, const unsigned short* __restrict__ eidx,
                        const float* __restrict__ feats3, const float* __restrict__ agg3ovf,
                        const float* __restrict__ iinv, const float* __restrict__ oinv,
                        const float* __restrict__ W0, const float* __restrict__ b0,
                        unsigned* __restrict__ hs, int n) {
    int t = blockIdx.x * blockDim.x + threadIdx.x;
    int i = t >> 5;
    if (i >= n) return;
    int q = t & 31;
    int deg = min(icnt[i], CAP);
    const unsigned short* row = eidx + i * CAP;
    float a0 = 0.f, a1 = 0.f, a2 = 0.f;
    for (int k = q; k < deg; k += 32) {
        int s = row[k];
        a0 += feats3[s * 3 + 0];
        a1 += feats3[s * 3 + 1];
        a2 += feats3[s * 3 + 2];
    }
    #pragma unroll
    for (int m = 1; m <= 16; m <<= 1) {
        a0 += __shfl_xor(a0, m);
        a1 += __shfl_xor(a1, m);
        a2 += __shfl_xor(a2, m);
    }
    a0 += agg3ovf[i * 3 + 0];
    a1 += agg3ovf[i * 3 + 1];
    a2 += agg3ovf[i * 3 + 2];
    float ii = iinv[i], oi = oinv[i];
    a0 *= ii; a1 *= ii; a2 *= ii;
    int j0 = q * 4;
    float4 w0r = *(const float4*)&W0[0 * DIM + j0];
    float4 w1r = *(const float4*)&W0[1 * DIM + j0];
    float4 w2r = *(const float4*)&W0[2 * DIM + j0];
    float4 bb  = *(const float4*)&b0[j0];
    float v0 = a0 * w0r.x + a1 * w1r.x + a2 * w2r.x + bb.x;
    float v1 = a0 * w0r.y + a1 * w1r.y + a2 * w2r.y + bb.y;
    float v2 = a0 * w0r.z + a1 * w1r.z + a2 * w2r.z + bb.z;
    float v3 = a0 * w0r.w + a1 * w1r.w + a2 * w2r.w + bb.w;
    v0 = v0 > 0.f ? v0 : NEG_SLOPE * v0;
    v1 = v1 > 0.f ? v1 : NEG_SLOPE * v1;
    v2 = v2 > 0.f ? v2 : NEG_SLOPE * v2;
    v3 = v3 > 0.f ? v3 : NEG_SLOPE * v3;
    ((uint2*)hs)[i * 32 + q] = make_uint2(f2b_rne2(v0 * oi, v1 * oi),
                                          f2b_rne2(v2 * oi, v3 * oi));
}

// ---------------- layer-2 aggregation: bucket gather -> aggbuf ----------------
__global__ void k_gather128(const int* __restrict__ icnt, const unsigned short* __restrict__ eidx,
                            const unsigned* __restrict__ hs, float* __restrict__ agg, int n) {
    int t = blockIdx.x * blockDim.x + threadIdx.x;
    int i = t >> 5;
    if (i >= n) return;
    int q = t & 31;
    int deg = min(icnt[i], CAP);
    const unsigned short* row = eidx + i * CAP;
    const uint2* hs2 = (const uint2*)hs;
    float a0 = 0.f, a1 = 0.f, a2 = 0.f, a3 = 0.f;
    int k = 0;
    for (; k + 2 <= deg; k += 2) {
        int s0 = row[k], s1 = row[k + 1];
        uint2 u0 = hs2[s0 * 32 + q];
        uint2 u1 = hs2[s1 * 32 + q];
        a0 += b2f_lo(u0.x) + b2f_lo(u1.x);
        a1 += b2f_hi(u0.x) + b2f_hi(u1.x);
        a2 += b2f_lo(u0.y) + b2f_lo(u1.y);
        a3 += b2f_hi(u0.y) + b2f_hi(u1.y);
    }
    if (k < deg) {
        int s = row[k];
        uint2 u = hs2[s * 32 + q];
        a0 += b2f_lo(u.x); a1 += b2f_hi(u.x);
        a2 += b2f_lo(u.y); a3 += b2f_hi(u.y);
    }
    ((float4*)agg)[i * 32 + q] = make_float4(a0, a1, a2, a3);
}

// ---------------- layer-2 overflow edges: atomic add into aggbuf ----------------
__global__ void k_overflow(const int* __restrict__ ovf_cnt, const int2* __restrict__ ovf,
                           const unsigned* __restrict__ hs, float* __restrict__ agg) {
    int g = blockIdx.x * blockDim.x + threadIdx.x;
    int entry = g >> 5, q = g & 31;
    int cnt = min(*ovf_cnt, OVF_MAX);
    if (entry >= cnt) return;
    int2 e = ovf[entry];                       // (dst, src)
    uint2 u = ((const uint2*)hs)[e.y * 32 + q];
    float* o = agg + (size_t)e.x * DIM + q * 4;
    atomicAdd(o + 0, b2f_lo(u.x));
    atomicAdd(o + 1, b2f_hi(u.x));
    atomicAdd(o + 2, b2f_lo(u.y));
    atomicAdd(o + 3, b2f_hi(u.y));
}

// ---------------- final: out = (agg * iinv) @ W1 + b1, column-split ----------------
// blockIdx: tile = bid>>1 (256 nodes), half = bid&1 (64 cols). sW = 32 KB ->
// 3-4 blocks/CU. 256 threads = 32 row-groups x 8 col-groups, 8x8 tile each.
// Out-of-place (agg -> out): no in-place race, clamped reads harmless.
#define FB_NODES 256
__global__ __launch_bounds__(256) void k_final(const float* __restrict__ iinv,
                                               const float* __restrict__ W1,
                                               const float* __restrict__ b1,
                                               const float* __restrict__ agg,
                                               float* __restrict__ out, int n) {
    __shared__ float sW[DIM * 64];         // 32 KB: W1[:, half*64 .. half*64+63]
    int tid = threadIdx.x;
    int half = blockIdx.x & 1;
    int tile = blockIdx.x >> 1;
    for (int idx = tid; idx < DIM * 64 / 4; idx += 256) {
        int r = idx >> 4, c4 = idx & 15;
        *(float4*)&sW[r * 64 + c4 * 4] = *(const float4*)&W1[r * DIM + half * 64 + c4 * 4];
    }
    int cg = tid & 7;                      // 8 col-groups of 8 cols
    int ng = tid >> 3;                     // 32 row-groups of 8 rows
    int col0 = cg * 8;                     // local col in [0,64)
    int row0 = tile * FB_NODES + ng * 8;

    float acc[8][8];
    #pragma unroll
    for (int i = 0; i < 8; ++i)
        #pragma unroll
        for (int j = 0; j < 8; ++j) acc[i][j] = 0.f;

    __syncthreads();

    const float4* agg4 = (const float4*)agg;
    for (int k4 = 0; k4 < 32; ++k4) {
        float4 a[8];
        #pragma unroll
        for (int i = 0; i < 8; ++i) {
            int r = min(row0 + i, n - 1);          // clamped read; store is guarded
            a[i] = agg4[(size_t)r * 32 + k4];
        }
        #pragma unroll
        for (int kk = 0; kk < 4; ++kk) {
            float4 w0 = *(const float4*)&sW[(k4 * 4 + kk) * 64 + col0];
            float4 w1v = *(const float4*)&sW[(k4 * 4 + kk) * 64 + col0 + 4];
            #pragma unroll
            for (int i = 0; i < 8; ++i) {
                float av = (kk == 0) ? a[i].x : (kk == 1) ? a[i].y : (kk == 2) ? a[i].z : a[i].w;
                acc[i][0] += av * w0.x;  acc[i][1] += av * w0.y;
                acc[i][2] += av * w0.z;  acc[i][3] += av * w0.w;
                acc[i][4] += av * w1v.x; acc[i][5] += av * w1v.y;
                acc[i][6] += av * w1v.z; acc[i][7] += av * w1v.w;
            }
        }
    }

    int gcol = half * 64 + col0;
    float4 bb0 = *(const float4*)&b1[gcol];
    float4 bb1 = *(const float4*)&b1[gcol + 4];
    #pragma unroll
    for (int i = 0; i < 8; ++i) {
        int r = row0 + i;
        if (r < n) {
            float ii = iinv[r];
            float4 o0, o1;
            o0.x = acc[i][0] * ii + bb0.x; o0.y = acc[i][1] * ii + bb0.y;
            o0.z = acc[i][2] * ii + bb0.z; o0.w = acc[i][3] * ii + bb0.w;
            o1.x = acc[i][4] * ii + bb1.x; o1.y = acc[i][5] * ii + bb1.y;
            o1.z = acc[i][6] * ii + bb1.z; o1.w = acc[i][7] * ii + bb1.w;
            ((float4*)out)[(size_t)r * 32 + (gcol >> 2)] = o0;
            ((float4*)out)[(size_t)r * 32 + (gcol >> 2) + 1] = o1;
        }
    }
}

// ---------------- launch ----------------
extern "C" void kernel_launch(void* const* d_in, const int* in_sizes, int n_in,
                              void* d_out, int out_size, void* d_ws, size_t ws_size,
                              hipStream_t stream) {
    const int*   src  = (const int*)d_in[0];
    const int*   dst  = (const int*)d_in[1];
    const float* weight = (const float*)d_in[2];
    const int*   sig  = (const int*)d_in[3];
    const float* emb  = (const float*)d_in[4];
    const float* W0   = (const float*)d_in[5];
    const float* b0   = (const float*)d_in[6];
    const float* W1   = (const float*)d_in[7];
    const float* b1   = (const float*)d_in[8];
    float* out = (float*)d_out;

    // ---- workspace layout (4B words); zeroed buffers first ----
    int*   icnt    = (int*)d_ws;                          // @0        50000 (memset)
    int*   ovf_cnt = icnt + N_NODES;                      // @50000    8     (memset)
    float* agg3ovf = (float*)(ovf_cnt + 8);               // @50008    150000 (memset)
    int2*  ovf     = (int2*)(agg3ovf + 3 * N_NODES);      // @200008   4096 int2 (byte %8==0)
    float* oinv    = (float*)(ovf + OVF_MAX);             // @208200   50000
    float* iinv    = oinv + N_NODES;                      // @258200   50000
    float* feats3  = iinv + N_NODES;                      // @308200   150000
    int*   partial = (int*)(feats3 + 3 * N_NODES);        // @458200   3203072
    unsigned short* eidx = (unsigned short*)(partial + (size_t)NR * SLICES * RNODES);
    unsigned* hs   = (unsigned*)(eidx + (size_t)N_NODES * CAP);     // 3.2M words
    float* aggbuf  = (float*)(hs + (size_t)N_NODES * 64);           // 6.4M words

    hipMemsetAsync(d_ws, 0, (size_t)(N_NODES + 8 + 3 * N_NODES) * 4, stream);

    k_fillbucket<<<(N_EDGES / 2 + 255) / 256, 256, 0, stream>>>(src, dst, icnt, eidx,
                                                                ovf_cnt, ovf, N_EDGES / 2);
    k_hist<<<NR * SLICES, 256, 0, stream>>>(src, partial);
    k_prep<<<(N_NODES + 255) / 256, 256, 0, stream>>>(weight, sig, emb, partial, icnt,
                                                      oinv, iinv, feats3, N_NODES);
    k_ovf3<<<(OVF_MAX + 255) / 256, 256, 0, stream>>>(ovf_cnt, ovf, feats3, agg3ovf);
    k_aggl1<<<(N_NODES * 32 + 255) / 256, 256, 0, stream>>>(icnt, eidx, feats3, agg3ovf,
                                                            iinv, oinv, W0, b0, hs, N_NODES);
    k_gather128<<<((N_NODES * 32) + 255) / 256, 256, 0, stream>>>(icnt, eidx, hs, aggbuf,
                                                                  N_NODES);
    k_overflow<<<(OVF_MAX * 32) / 256, 256, 0, stream>>>(ovf_cnt, ovf, hs, aggbuf);
    k_final<<<((N_NODES + FB_NODES - 1) / FB_NODES) * 2, 256, 0, stream>>>(
        iinv, W1, b1, aggbuf, out, N_NODES);
}

// Round 13
// 142.384 us; speedup vs baseline: 9.0277x; 1.1005x over previous
//
#include <hip/hip_runtime.h>

#define N_NODES 50000
#define N_EDGES 800000
#define DIM 128
#define NEG_SLOPE 0.01f
#define CAP 32           // bucket capacity
#define OVF_MAX 4096     // overflow list capacity (expected usage: tens)

// ---- range/slice partitioning ----
#define NR 4             // node ranges
#define RNODES 12512     // nodes per range (4*12512 = 50048 >= 50000), LDS 50 KB
#define SLICES 64        // edge slices
#define ESLICE (N_EDGES / SLICES)   // 12500 edges per slice

// ---- bf16 pack/unpack (RNE) ----
__device__ inline unsigned f2b_rne2(float a, float b) {
    unsigned ua = __float_as_uint(a), ub = __float_as_uint(b);
    ua = (ua + 0x7fffu + ((ua >> 16) & 1u)) >> 16;
    ub = (ub + 0x7fffu + ((ub >> 16) & 1u)) >> 16;
    return ua | (ub << 16);
}
__device__ inline float b2f_lo(unsigned u) { return __uint_as_float(u << 16); }
__device__ inline float b2f_hi(unsigned u) { return __uint_as_float(u & 0xffff0000u); }

// ---------------- dual histogram: src + dst per (range, slice), LDS-privatized ----------------
__global__ __launch_bounds__(512) void k_hist2(const int* __restrict__ src,
                                               const int* __restrict__ dst,
                                               int* __restrict__ pSrc, int* __restrict__ pDst) {
    __shared__ int bs[RNODES];             // 50 KB src bins
    __shared__ int bd[RNODES];             // 50 KB dst bins
    int range = blockIdx.x / SLICES;
    int slice = blockIdx.x % SLICES;
    int tid = threadIdx.x;
    for (int j = tid; j < RNODES; j += 512) { bs[j] = 0; bd[j] = 0; }
    __syncthreads();
    int base = range * RNODES;
    const int4* s4 = (const int4*)(src + slice * ESLICE);
    const int4* d4 = (const int4*)(dst + slice * ESLICE);
    for (int t = tid; t < ESLICE / 4; t += 512) {
        int4 v = s4[t];
        unsigned u0 = (unsigned)(v.x - base), u1 = (unsigned)(v.y - base);
        unsigned u2 = (unsigned)(v.z - base), u3 = (unsigned)(v.w - base);
        if (u0 < RNODES) atomicAdd(&bs[u0], 1);
        if (u1 < RNODES) atomicAdd(&bs[u1], 1);
        if (u2 < RNODES) atomicAdd(&bs[u2], 1);
        if (u3 < RNODES) atomicAdd(&bs[u3], 1);
        int4 w = d4[t];
        unsigned w0 = (unsigned)(w.x - base), w1 = (unsigned)(w.y - base);
        unsigned w2 = (unsigned)(w.z - base), w3 = (unsigned)(w.w - base);
        if (w0 < RNODES) atomicAdd(&bd[w0], 1);
        if (w1 < RNODES) atomicAdd(&bd[w1], 1);
        if (w2 < RNODES) atomicAdd(&bd[w2], 1);
        if (w3 < RNODES) atomicAdd(&bd[w3], 1);
    }
    __syncthreads();
    int* os = pSrc + (size_t)blockIdx.x * RNODES;
    int* od = pDst + (size_t)blockIdx.x * RNODES;
    for (int j = tid; j < RNODES; j += 512) { os[j] = bs[j]; od[j] = bd[j]; }
}

// ---------------- scan dst partials (in place, per node) + fused prep ----------------
// thread g = node id (range = g/RNODES, off = g%RNODES). Writes exclusive prefix
// per slice back into pDst; totals -> icnt (no memset needed), degrees -> oinv/iinv/feats3.
__global__ void k_scanprep(const float* __restrict__ weight, const int* __restrict__ sig,
                           const float* __restrict__ emb,
                           const int* __restrict__ pSrc, int* __restrict__ pDst,
                           int* __restrict__ icnt, float* __restrict__ oinv,
                           float* __restrict__ iinv, float* __restrict__ feats3, int n) {
    int g = blockIdx.x * blockDim.x + threadIdx.x;
    if (g >= NR * RNODES) return;
    int range = g / RNODES, off = g % RNODES;
    size_t basei = (size_t)(range * SLICES) * RNODES + off;
    int run = 0;
    #pragma unroll 8
    for (int s = 0; s < SLICES; ++s) {
        size_t idx = basei + (size_t)s * RNODES;
        int c = pDst[idx];
        pDst[idx] = run;                   // exclusive prefix for slice s
        run += c;
    }
    int od = 0;
    #pragma unroll 8
    for (int s = 0; s < SLICES; ++s) od += pSrc[basei + (size_t)s * RNODES];
    if (g < n) {
        icnt[g] = run;                     // total in-degree
        float oi = 1.0f / sqrtf((float)max(od, 1));
        oinv[g] = oi;
        iinv[g] = 1.0f / sqrtf((float)max(run, 1));
        int sg = sig[g];
        feats3[g * 3 + 0] = weight[g] * oi;
        feats3[g * 3 + 1] = emb[sg * 2 + 0] * oi;
        feats3[g * 3 + 2] = emb[sg * 2 + 1] * oi;
    }
}

// ---------------- atomic-free bucket fill: LDS prefix-cursors ----------------
// block (range, slice): cursors pre-initialized with the exclusive prefix ->
// p = ldsAtomicAdd gives globally-unique slot 0..deg-1 for each edge. Plain stores.
__global__ __launch_bounds__(512) void k_fill3(const int* __restrict__ src,
                                               const int* __restrict__ dst,
                                               const int* __restrict__ pDst,
                                               unsigned short* __restrict__ eidx,
                                               int* __restrict__ ovf_cnt, int2* __restrict__ ovf) {
    __shared__ int cur[RNODES];            // 50 KB prefix-initialized cursors
    int range = blockIdx.x / SLICES;
    int slice = blockIdx.x % SLICES;
    int tid = threadIdx.x;
    const int* pr = pDst + (size_t)blockIdx.x * RNODES;
    for (int j = tid; j < RNODES; j += 512) cur[j] = pr[j];
    __syncthreads();
    int base = range * RNODES;
    const int* ss = src + slice * ESLICE;
    const int* dd = dst + slice * ESLICE;
    for (int t = tid; t < ESLICE; t += 512) {
        int d = dd[t];
        unsigned u = (unsigned)(d - base);
        if (u < RNODES) {
            int s = ss[t];
            int p = atomicAdd(&cur[u], 1);
            if (p < CAP) eidx[(size_t)d * CAP + p] = (unsigned short)s;
            else { int o = atomicAdd(ovf_cnt, 1); if (o < OVF_MAX) ovf[o] = make_int2(d, s); }
        }
    }
}

// ---------------- layer-1 overflow patch: agg3ovf[dst] += feats3[src] ----------------
__global__ void k_ovf3(const int* __restrict__ ovf_cnt, const int2* __restrict__ ovf,
                       const float* __restrict__ feats3, float* __restrict__ agg3ovf) {
    int t = blockIdx.x * blockDim.x + threadIdx.x;
    int cnt = min(*ovf_cnt, OVF_MAX);
    if (t >= cnt) return;
    int2 e = ovf[t];                           // (dst, src)
    atomicAdd(&agg3ovf[e.x * 3 + 0], feats3[e.y * 3 + 0]);
    atomicAdd(&agg3ovf[e.x * 3 + 1], feats3[e.y * 3 + 1]);
    atomicAdd(&agg3ovf[e.x * 3 + 2], feats3[e.y * 3 + 2]);
}

// ---------------- fused layer-1: agg3 gather + (.@W0+b0) + lrelu + bf16 pack ----------------
__global__ void k_aggl1(const int* __restrict__ icnt, const unsigned short* __restrict__ eidx,
                        const float* __restrict__ feats3, const float* __restrict__ agg3ovf,
                        const float* __restrict__ iinv, const float* __restrict__ oinv,
                        const float* __restrict__ W0, const float* __restrict__ b0,
                        unsigned* __restrict__ hs, int n) {
    int t = blockIdx.x * blockDim.x + threadIdx.x;
    int i = t >> 5;
    if (i >= n) return;
    int q = t & 31;
    int deg = min(icnt[i], CAP);
    const unsigned short* row = eidx + i * CAP;
    float a0 = 0.f, a1 = 0.f, a2 = 0.f;
    for (int k = q; k < deg; k += 32) {
        int s = row[k];
        a0 += feats3[s * 3 + 0];
        a1 += feats3[s * 3 + 1];
        a2 += feats3[s * 3 + 2];
    }
    #pragma unroll
    for (int m = 1; m <= 16; m <<= 1) {
        a0 += __shfl_xor(a0, m);
        a1 += __shfl_xor(a1, m);
        a2 += __shfl_xor(a2, m);
    }
    a0 += agg3ovf[i * 3 + 0];
    a1 += agg3ovf[i * 3 + 1];
    a2 += agg3ovf[i * 3 + 2];
    float ii = iinv[i], oi = oinv[i];
    a0 *= ii; a1 *= ii; a2 *= ii;
    int j0 = q * 4;
    float4 w0r = *(const float4*)&W0[0 * DIM + j0];
    float4 w1r = *(const float4*)&W0[1 * DIM + j0];
    float4 w2r = *(const float4*)&W0[2 * DIM + j0];
    float4 bb  = *(const float4*)&b0[j0];
    float v0 = a0 * w0r.x + a1 * w1r.x + a2 * w2r.x + bb.x;
    float v1 = a0 * w0r.y + a1 * w1r.y + a2 * w2r.y + bb.y;
    float v2 = a0 * w0r.z + a1 * w1r.z + a2 * w2r.z + bb.z;
    float v3 = a0 * w0r.w + a1 * w1r.w + a2 * w2r.w + bb.w;
    v0 = v0 > 0.f ? v0 : NEG_SLOPE * v0;
    v1 = v1 > 0.f ? v1 : NEG_SLOPE * v1;
    v2 = v2 > 0.f ? v2 : NEG_SLOPE * v2;
    v3 = v3 > 0.f ? v3 : NEG_SLOPE * v3;
    ((uint2*)hs)[i * 32 + q] = make_uint2(f2b_rne2(v0 * oi, v1 * oi),
                                          f2b_rne2(v2 * oi, v3 * oi));
}

// ---------------- layer-2 aggregation: bucket gather -> aggbuf ----------------
__global__ void k_gather128(const int* __restrict__ icnt, const unsigned short* __restrict__ eidx,
                            const unsigned* __restrict__ hs, float* __restrict__ agg, int n) {
    int t = blockIdx.x * blockDim.x + threadIdx.x;
    int i = t >> 5;
    if (i >= n) return;
    int q = t & 31;
    int deg = min(icnt[i], CAP);
    const unsigned short* row = eidx + i * CAP;
    const uint2* hs2 = (const uint2*)hs;
    float a0 = 0.f, a1 = 0.f, a2 = 0.f, a3 = 0.f;
    int k = 0;
    for (; k + 2 <= deg; k += 2) {
        int s0 = row[k], s1 = row[k + 1];
        uint2 u0 = hs2[s0 * 32 + q];
        uint2 u1 = hs2[s1 * 32 + q];
        a0 += b2f_lo(u0.x) + b2f_lo(u1.x);
        a1 += b2f_hi(u0.x) + b2f_hi(u1.x);
        a2 += b2f_lo(u0.y) + b2f_lo(u1.y);
        a3 += b2f_hi(u0.y) + b2f_hi(u1.y);
    }
    if (k < deg) {
        int s = row[k];
        uint2 u = hs2[s * 32 + q];
        a0 += b2f_lo(u.x); a1 += b2f_hi(u.x);
        a2 += b2f_lo(u.y); a3 += b2f_hi(u.y);
    }
    ((float4*)agg)[i * 32 + q] = make_float4(a0, a1, a2, a3);
}

// ---------------- layer-2 overflow edges: atomic add into aggbuf ----------------
__global__ void k_overflow(const int* __restrict__ ovf_cnt, const int2* __restrict__ ovf,
                           const unsigned* __restrict__ hs, float* __restrict__ agg) {
    int g = blockIdx.x * blockDim.x + threadIdx.x;
    int entry = g >> 5, q = g & 31;
    int cnt = min(*ovf_cnt, OVF_MAX);
    if (entry >= cnt) return;
    int2 e = ovf[entry];                       // (dst, src)
    uint2 u = ((const uint2*)hs)[e.y * 32 + q];
    float* o = agg + (size_t)e.x * DIM + q * 4;
    atomicAdd(o + 0, b2f_lo(u.x));
    atomicAdd(o + 1, b2f_hi(u.x));
    atomicAdd(o + 2, b2f_lo(u.y));
    atomicAdd(o + 3, b2f_hi(u.y));
}

// ---------------- final: out = (agg * iinv) @ W1 + b1, column-split ----------------
#define FB_NODES 256
__global__ __launch_bounds__(256) void k_final(const float* __restrict__ iinv,
                                               const float* __restrict__ W1,
                                               const float* __restrict__ b1,
                                               const float* __restrict__ agg,
                                               float* __restrict__ out, int n) {
    __shared__ float sW[DIM * 64];         // 32 KB: W1[:, half*64 .. half*64+63]
    int tid = threadIdx.x;
    int half = blockIdx.x & 1;
    int tile = blockIdx.x >> 1;
    for (int idx = tid; idx < DIM * 64 / 4; idx += 256) {
        int r = idx >> 4, c4 = idx & 15;
        *(float4*)&sW[r * 64 + c4 * 4] = *(const float4*)&W1[r * DIM + half * 64 + c4 * 4];
    }
    int cg = tid & 7;                      // 8 col-groups of 8 cols
    int ng = tid >> 3;                     // 32 row-groups of 8 rows
    int col0 = cg * 8;
    int row0 = tile * FB_NODES + ng * 8;

    float acc[8][8];
    #pragma unroll
    for (int i = 0; i < 8; ++i)
        #pragma unroll
        for (int j = 0; j < 8; ++j) acc[i][j] = 0.f;

    __syncthreads();

    const float4* agg4 = (const float4*)agg;
    for (int k4 = 0; k4 < 32; ++k4) {
        float4 a[8];
        #pragma unroll
        for (int i = 0; i < 8; ++i) {
            int r = min(row0 + i, n - 1);          // clamped read; store is guarded
            a[i] = agg4[(size_t)r * 32 + k4];
        }
        #pragma unroll
        for (int kk = 0; kk < 4; ++kk) {
            float4 w0 = *(const float4*)&sW[(k4 * 4 + kk) * 64 + col0];
            float4 w1v = *(const float4*)&sW[(k4 * 4 + kk) * 64 + col0 + 4];
            #pragma unroll
            for (int i = 0; i < 8; ++i) {
                float av = (kk == 0) ? a[i].x : (kk == 1) ? a[i].y : (kk == 2) ? a[i].z : a[i].w;
                acc[i][0] += av * w0.x;  acc[i][1] += av * w0.y;
                acc[i][2] += av * w0.z;  acc[i][3] += av * w0.w;
                acc[i][4] += av * w1v.x; acc[i][5] += av * w1v.y;
                acc[i][6] += av * w1v.z; acc[i][7] += av * w1v.w;
            }
        }
    }

    int gcol = half * 64 + col0;
    float4 bb0 = *(const float4*)&b1[gcol];
    float4 bb1 = *(const float4*)&b1[gcol + 4];
    #pragma unroll
    for (int i = 0; i < 8; ++i) {
        int r = row0 + i;
        if (r < n) {
            float ii = iinv[r];
            float4 o0, o1;
            o0.x = acc[i][0] * ii + bb0.x; o0.y = acc[i][1] * ii + bb0.y;
            o0.z = acc[i][2] * ii + bb0.z; o0.w = acc[i][3] * ii + bb0.w;
            o1.x = acc[i][4] * ii + bb1.x; o1.y = acc[i][5] * ii + bb1.y;
            o1.z = acc[i][6] * ii + bb1.z; o1.w = acc[i][7] * ii + bb1.w;
            ((float4*)out)[(size_t)r * 32 + (gcol >> 2)] = o0;
            ((float4*)out)[(size_t)r * 32 + (gcol >> 2) + 1] = o1;
        }
    }
}

// ---------------- launch ----------------
extern "C" void kernel_launch(void* const* d_in, const int* in_sizes, int n_in,
                              void* d_out, int out_size, void* d_ws, size_t ws_size,
                              hipStream_t stream) {
    const int*   src  = (const int*)d_in[0];
    const int*   dst  = (const int*)d_in[1];
    const float* weight = (const float*)d_in[2];
    const int*   sig  = (const int*)d_in[3];
    const float* emb  = (const float*)d_in[4];
    const float* W0   = (const float*)d_in[5];
    const float* b0   = (const float*)d_in[6];
    const float* W1   = (const float*)d_in[7];
    const float* b1   = (const float*)d_in[8];
    float* out = (float*)d_out;

    // ---- workspace layout (4B words); zeroed buffers first ----
    int*   ovf_cnt = (int*)d_ws;                          // @0        8      (memset)
    float* agg3ovf = (float*)(ovf_cnt + 8);               // @8        150000 (memset)
    int2*  ovf     = (int2*)(agg3ovf + 3 * N_NODES);      // @150008   4096 int2 (byte %8==0)
    int*   icnt    = (int*)(ovf + OVF_MAX);               // @158200   50000
    float* oinv    = (float*)(icnt + N_NODES);            // @208200   50000
    float* iinv    = oinv + N_NODES;                      // @258200   50000
    float* feats3  = iinv + N_NODES;                      // @308200   150000
    int*   pSrc    = (int*)(feats3 + 3 * N_NODES);        // @458200   3,203,072
    int*   pDst    = pSrc + (size_t)NR * SLICES * RNODES; //           3,203,072
    unsigned short* eidx = (unsigned short*)(pDst + (size_t)NR * SLICES * RNODES);
    unsigned* hs   = (unsigned*)(eidx + (size_t)N_NODES * CAP);     // 3.2M words
    float* aggbuf  = (float*)(hs + (size_t)N_NODES * 64);           // 6.4M words

    hipMemsetAsync(d_ws, 0, (size_t)(8 + 3 * N_NODES) * 4, stream); // ovf_cnt + agg3ovf

    k_hist2<<<NR * SLICES, 512, 0, stream>>>(src, dst, pSrc, pDst);
    k_scanprep<<<(NR * RNODES + 255) / 256, 256, 0, stream>>>(weight, sig, emb, pSrc, pDst,
                                                              icnt, oinv, iinv, feats3,
                                                              N_NODES);
    k_fill3<<<NR * SLICES, 512, 0, stream>>>(src, dst, pDst, eidx, ovf_cnt, ovf);
    k_ovf3<<<(OVF_MAX + 255) / 256, 256, 0, stream>>>(ovf_cnt, ovf, feats3, agg3ovf);
    k_aggl1<<<(N_NODES * 32 + 255) / 256, 256, 0, stream>>>(icnt, eidx, feats3, agg3ovf,
                                                            iinv, oinv, W0, b0, hs, N_NODES);
    k_gather128<<<((N_NODES * 32) + 255) / 256, 256, 0, stream>>>(icnt, eidx, hs, aggbuf,
                                                                  N_NODES);
    k_overflow<<<(OVF_MAX * 32) / 256, 256, 0, stream>>>(ovf_cnt, ovf, hs, aggbuf);
    k_final<<<((N_NODES + FB_NODES - 1) / FB_NODES) * 2, 256, 0, stream>>>(
        iinv, W1, b1, aggbuf, out, N_NODES);
}

// Round 14
// 132.898 us; speedup vs baseline: 9.6721x; 1.0714x over previous
//
#include <hip/hip_runtime.h>

#define N_NODES 50000
#define N_EDGES 800000
#define DIM 128
#define NEG_SLOPE 0.01f
#define CAP 32           // bucket capacity
#define OVF_MAX 4096     // overflow list capacity (expected usage: tens)

// ---- range/slice partitioning ----
#define NR 4             // node ranges
#define RNODES 12512     // nodes per range (4*12512 = 50048 >= 50000), LDS 50 KB
#define SLICES 64        // edge slices
#define ESLICE (N_EDGES / SLICES)   // 12500 edges per slice

// ---- bf16 pack/unpack (RNE) ----
__device__ inline unsigned f2b_rne2(float a, float b) {
    unsigned ua = __float_as_uint(a), ub = __float_as_uint(b);
    ua = (ua + 0x7fffu + ((ua >> 16) & 1u)) >> 16;
    ub = (ub + 0x7fffu + ((ub >> 16) & 1u)) >> 16;
    return ua | (ub << 16);
}
__device__ inline float b2f_lo(unsigned u) { return __uint_as_float(u << 16); }
__device__ inline float b2f_hi(unsigned u) { return __uint_as_float(u & 0xffff0000u); }

// ---------------- dual histogram: src + dst per (range, slice), LDS-privatized ----------------
__global__ __launch_bounds__(512) void k_hist2(const int* __restrict__ src,
                                               const int* __restrict__ dst,
                                               int* __restrict__ pSrc, int* __restrict__ pDst) {
    __shared__ int bs[RNODES];             // 50 KB src bins
    __shared__ int bd[RNODES];             // 50 KB dst bins
    int range = blockIdx.x / SLICES;
    int slice = blockIdx.x % SLICES;
    int tid = threadIdx.x;
    for (int j = tid; j < RNODES; j += 512) { bs[j] = 0; bd[j] = 0; }
    __syncthreads();
    int base = range * RNODES;
    const int4* s4 = (const int4*)(src + slice * ESLICE);
    const int4* d4 = (const int4*)(dst + slice * ESLICE);
    for (int t = tid; t < ESLICE / 4; t += 512) {
        int4 v = s4[t];
        unsigned u0 = (unsigned)(v.x - base), u1 = (unsigned)(v.y - base);
        unsigned u2 = (unsigned)(v.z - base), u3 = (unsigned)(v.w - base);
        if (u0 < RNODES) atomicAdd(&bs[u0], 1);
        if (u1 < RNODES) atomicAdd(&bs[u1], 1);
        if (u2 < RNODES) atomicAdd(&bs[u2], 1);
        if (u3 < RNODES) atomicAdd(&bs[u3], 1);
        int4 w = d4[t];
        unsigned w0 = (unsigned)(w.x - base), w1 = (unsigned)(w.y - base);
        unsigned w2 = (unsigned)(w.z - base), w3 = (unsigned)(w.w - base);
        if (w0 < RNODES) atomicAdd(&bd[w0], 1);
        if (w1 < RNODES) atomicAdd(&bd[w1], 1);
        if (w2 < RNODES) atomicAdd(&bd[w2], 1);
        if (w3 < RNODES) atomicAdd(&bd[w3], 1);
    }
    __syncthreads();
    int* os = pSrc + (size_t)blockIdx.x * RNODES;
    int* od = pDst + (size_t)blockIdx.x * RNODES;
    for (int j = tid; j < RNODES; j += 512) { os[j] = bs[j]; od[j] = bd[j]; }
}

// ---------------- scan dst partials (in place) + fused prep + ovf_cnt reset ----------------
__global__ void k_scanprep(const float* __restrict__ weight, const int* __restrict__ sig,
                           const float* __restrict__ emb,
                           const int* __restrict__ pSrc, int* __restrict__ pDst,
                           int* __restrict__ icnt, float* __restrict__ oinv,
                           float* __restrict__ iinv, float* __restrict__ feats3,
                           int* __restrict__ ovf_cnt, int n) {
    int g = blockIdx.x * blockDim.x + threadIdx.x;
    if (g == 0) *ovf_cnt = 0;              // runs before k_fill3 on the stream
    if (g >= NR * RNODES) return;
    int range = g / RNODES, off = g % RNODES;
    size_t basei = (size_t)(range * SLICES) * RNODES + off;
    int run = 0;
    #pragma unroll 8
    for (int s = 0; s < SLICES; ++s) {
        size_t idx = basei + (size_t)s * RNODES;
        int c = pDst[idx];
        pDst[idx] = run;                   // exclusive prefix for slice s
        run += c;
    }
    int od = 0;
    #pragma unroll 8
    for (int s = 0; s < SLICES; ++s) od += pSrc[basei + (size_t)s * RNODES];
    if (g < n) {
        icnt[g] = run;                     // total in-degree
        float oi = 1.0f / sqrtf((float)max(od, 1));
        oinv[g] = oi;
        iinv[g] = 1.0f / sqrtf((float)max(run, 1));
        int sg = sig[g];
        feats3[g * 3 + 0] = weight[g] * oi;
        feats3[g * 3 + 1] = emb[sg * 2 + 0] * oi;
        feats3[g * 3 + 2] = emb[sg * 2 + 1] * oi;
    }
}

// ---------------- atomic-free bucket fill: LDS prefix-cursors ----------------
__global__ __launch_bounds__(512) void k_fill3(const int* __restrict__ src,
                                               const int* __restrict__ dst,
                                               const int* __restrict__ pDst,
                                               unsigned short* __restrict__ eidx,
                                               int* __restrict__ ovf_cnt, int2* __restrict__ ovf) {
    __shared__ int cur[RNODES];            // 50 KB prefix-initialized cursors
    int range = blockIdx.x / SLICES;
    int slice = blockIdx.x % SLICES;
    int tid = threadIdx.x;
    const int* pr = pDst + (size_t)blockIdx.x * RNODES;
    for (int j = tid; j < RNODES; j += 512) cur[j] = pr[j];
    __syncthreads();
    int base = range * RNODES;
    const int* ss = src + slice * ESLICE;
    const int* dd = dst + slice * ESLICE;
    for (int t = tid; t < ESLICE; t += 512) {
        int d = dd[t];
        unsigned u = (unsigned)(d - base);
        if (u < RNODES) {
            int s = ss[t];
            int p = atomicAdd(&cur[u], 1);
            if (p < CAP) eidx[(size_t)d * CAP + p] = (unsigned short)s;
            else { int o = atomicAdd(ovf_cnt, 1); if (o < OVF_MAX) ovf[o] = make_int2(d, s); }
        }
    }
}

// ---------------- fused layer-1: gather + ovf-fold + (.@W0+b0) + lrelu + bf16 pack ----------------
__global__ void k_aggl1(const int* __restrict__ icnt, const unsigned short* __restrict__ eidx,
                        const float* __restrict__ feats3,
                        const int* __restrict__ ovf_cnt, const int2* __restrict__ ovf,
                        const float* __restrict__ iinv, const float* __restrict__ oinv,
                        const float* __restrict__ W0, const float* __restrict__ b0,
                        unsigned* __restrict__ hs, int n) {
    int t = blockIdx.x * blockDim.x + threadIdx.x;
    int i = t >> 5;
    if (i >= n) return;
    int q = t & 31;
    int ic = icnt[i];
    int deg = min(ic, CAP);
    const unsigned short* row = eidx + i * CAP;
    float a0 = 0.f, a1 = 0.f, a2 = 0.f;
    for (int k = q; k < deg; k += 32) {
        int s = row[k];
        a0 += feats3[s * 3 + 0];
        a1 += feats3[s * 3 + 1];
        a2 += feats3[s * 3 + 2];
    }
    if (ic > CAP) {                        // rare (~6 nodes): fold overflow edges
        int cnt = min(*ovf_cnt, OVF_MAX);
        for (int e = q; e < cnt; e += 32) {
            int2 ov = ovf[e];              // (dst, src)
            if (ov.x == i) {
                a0 += feats3[ov.y * 3 + 0];
                a1 += feats3[ov.y * 3 + 1];
                a2 += feats3[ov.y * 3 + 2];
            }
        }
    }
    #pragma unroll
    for (int m = 1; m <= 16; m <<= 1) {
        a0 += __shfl_xor(a0, m);
        a1 += __shfl_xor(a1, m);
        a2 += __shfl_xor(a2, m);
    }
    float ii = iinv[i], oi = oinv[i];
    a0 *= ii; a1 *= ii; a2 *= ii;
    int j0 = q * 4;
    float4 w0r = *(const float4*)&W0[0 * DIM + j0];
    float4 w1r = *(const float4*)&W0[1 * DIM + j0];
    float4 w2r = *(const float4*)&W0[2 * DIM + j0];
    float4 bb  = *(const float4*)&b0[j0];
    float v0 = a0 * w0r.x + a1 * w1r.x + a2 * w2r.x + bb.x;
    float v1 = a0 * w0r.y + a1 * w1r.y + a2 * w2r.y + bb.y;
    float v2 = a0 * w0r.z + a1 * w1r.z + a2 * w2r.z + bb.z;
    float v3 = a0 * w0r.w + a1 * w1r.w + a2 * w2r.w + bb.w;
    v0 = v0 > 0.f ? v0 : NEG_SLOPE * v0;
    v1 = v1 > 0.f ? v1 : NEG_SLOPE * v1;
    v2 = v2 > 0.f ? v2 : NEG_SLOPE * v2;
    v3 = v3 > 0.f ? v3 : NEG_SLOPE * v3;
    ((uint2*)hs)[i * 32 + q] = make_uint2(f2b_rne2(v0 * oi, v1 * oi),
                                          f2b_rne2(v2 * oi, v3 * oi));
}

// ---------------- layer-2 aggregation: bucket gather + ovf-fold -> aggbuf ----------------
__global__ void k_gather128(const int* __restrict__ icnt, const unsigned short* __restrict__ eidx,
                            const unsigned* __restrict__ hs,
                            const int* __restrict__ ovf_cnt, const int2* __restrict__ ovf,
                            float* __restrict__ agg, int n) {
    int t = blockIdx.x * blockDim.x + threadIdx.x;
    int i = t >> 5;
    if (i >= n) return;
    int q = t & 31;
    int ic = icnt[i];
    int deg = min(ic, CAP);
    const unsigned short* row = eidx + i * CAP;
    const uint2* hs2 = (const uint2*)hs;
    float a0 = 0.f, a1 = 0.f, a2 = 0.f, a3 = 0.f;
    int k = 0;
    for (; k + 2 <= deg; k += 2) {
        int s0 = row[k], s1 = row[k + 1];
        uint2 u0 = hs2[s0 * 32 + q];
        uint2 u1 = hs2[s1 * 32 + q];
        a0 += b2f_lo(u0.x) + b2f_lo(u1.x);
        a1 += b2f_hi(u0.x) + b2f_hi(u1.x);
        a2 += b2f_lo(u0.y) + b2f_lo(u1.y);
        a3 += b2f_hi(u0.y) + b2f_hi(u1.y);
    }
    if (k < deg) {
        int s = row[k];
        uint2 u = hs2[s * 32 + q];
        a0 += b2f_lo(u.x); a1 += b2f_hi(u.x);
        a2 += b2f_lo(u.y); a3 += b2f_hi(u.y);
    }
    if (ic > CAP) {                        // rare: fold overflow edges
        int cnt = min(*ovf_cnt, OVF_MAX);
        for (int e = 0; e < cnt; ++e) {
            int2 ov = ovf[e];              // (dst, src)
            if (ov.x == i) {
                uint2 u = hs2[ov.y * 32 + q];
                a0 += b2f_lo(u.x); a1 += b2f_hi(u.x);
                a2 += b2f_lo(u.y); a3 += b2f_hi(u.y);
            }
        }
    }
    ((float4*)agg)[i * 32 + q] = make_float4(a0, a1, a2, a3);
}

// ---------------- final: out = (agg * iinv) @ W1 + b1, column-split ----------------
#define FB_NODES 256
__global__ __launch_bounds__(256) void k_final(const float* __restrict__ iinv,
                                               const float* __restrict__ W1,
                                               const float* __restrict__ b1,
                                               const float* __restrict__ agg,
                                               float* __restrict__ out, int n) {
    __shared__ float sW[DIM * 64];         // 32 KB: W1[:, half*64 .. half*64+63]
    int tid = threadIdx.x;
    int half = blockIdx.x & 1;
    int tile = blockIdx.x >> 1;
    for (int idx = tid; idx < DIM * 64 / 4; idx += 256) {
        int r = idx >> 4, c4 = idx & 15;
        *(float4*)&sW[r * 64 + c4 * 4] = *(const float4*)&W1[r * DIM + half * 64 + c4 * 4];
    }
    int cg = tid & 7;                      // 8 col-groups of 8 cols
    int ng = tid >> 3;                     // 32 row-groups of 8 rows
    int col0 = cg * 8;
    int row0 = tile * FB_NODES + ng * 8;

    float acc[8][8];
    #pragma unroll
    for (int i = 0; i < 8; ++i)
        #pragma unroll
        for (int j = 0; j < 8; ++j) acc[i][j] = 0.f;

    __syncthreads();

    const float4* agg4 = (const float4*)agg;
    for (int k4 = 0; k4 < 32; ++k4) {
        float4 a[8];
        #pragma unroll
        for (int i = 0; i < 8; ++i) {
            int r = min(row0 + i, n - 1);          // clamped read; store is guarded
            a[i] = agg4[(size_t)r * 32 + k4];
        }
        #pragma unroll
        for (int kk = 0; kk < 4; ++kk) {
            float4 w0 = *(const float4*)&sW[(k4 * 4 + kk) * 64 + col0];
            float4 w1v = *(const float4*)&sW[(k4 * 4 + kk) * 64 + col0 + 4];
            #pragma unroll
            for (int i = 0; i < 8; ++i) {
                float av = (kk == 0) ? a[i].x : (kk == 1) ? a[i].y : (kk == 2) ? a[i].z : a[i].w;
                acc[i][0] += av * w0.x;  acc[i][1] += av * w0.y;
                acc[i][2] += av * w0.z;  acc[i][3] += av * w0.w;
                acc[i][4] += av * w1v.x; acc[i][5] += av * w1v.y;
                acc[i][6] += av * w1v.z; acc[i][7] += av * w1v.w;
            }
        }
    }

    int gcol = half * 64 + col0;
    float4 bb0 = *(const float4*)&b1[gcol];
    float4 bb1 = *(const float4*)&b1[gcol + 4];
    #pragma unroll
    for (int i = 0; i < 8; ++i) {
        int r = row0 + i;
        if (r < n) {
            float ii = iinv[r];
            float4 o0, o1;
            o0.x = acc[i][0] * ii + bb0.x; o0.y = acc[i][1] * ii + bb0.y;
            o0.z = acc[i][2] * ii + bb0.z; o0.w = acc[i][3] * ii + bb0.w;
            o1.x = acc[i][4] * ii + bb1.x; o1.y = acc[i][5] * ii + bb1.y;
            o1.z = acc[i][6] * ii + bb1.z; o1.w = acc[i][7] * ii + bb1.w;
            ((float4*)out)[(size_t)r * 32 + (gcol >> 2)] = o0;
            ((float4*)out)[(size_t)r * 32 + (gcol >> 2) + 1] = o1;
        }
    }
}

// ---------------- launch ----------------
extern "C" void kernel_launch(void* const* d_in, const int* in_sizes, int n_in,
                              void* d_out, int out_size, void* d_ws, size_t ws_size,
                              hipStream_t stream) {
    const int*   src  = (const int*)d_in[0];
    const int*   dst  = (const int*)d_in[1];
    const float* weight = (const float*)d_in[2];
    const int*   sig  = (const int*)d_in[3];
    const float* emb  = (const float*)d_in[4];
    const float* W0   = (const float*)d_in[5];
    const float* b0   = (const float*)d_in[6];
    const float* W1   = (const float*)d_in[7];
    const float* b1   = (const float*)d_in[8];
    float* out = (float*)d_out;

    // ---- workspace layout (4B words); no memsets needed ----
    int*   ovf_cnt = (int*)d_ws;                          // @0        8 (zeroed by k_scanprep)
    int2*  ovf     = (int2*)(ovf_cnt + 8);                // @8        4096 int2 (byte %8==0)
    int*   icnt    = (int*)(ovf + OVF_MAX);               // @8200     50000
    float* oinv    = (float*)(icnt + N_NODES);            // @58200    50000
    float* iinv    = oinv + N_NODES;                      // @108200   50000
    float* feats3  = iinv + N_NODES;                      // @158200   150000
    int*   pSrc    = (int*)(feats3 + 3 * N_NODES);        // @308200   3,203,072
    int*   pDst    = pSrc + (size_t)NR * SLICES * RNODES;
    unsigned short* eidx = (unsigned short*)(pDst + (size_t)NR * SLICES * RNODES);
    unsigned* hs   = (unsigned*)(eidx + (size_t)N_NODES * CAP);     // 3.2M words
    float* aggbuf  = (float*)(hs + (size_t)N_NODES * 64);           // 6.4M words

    k_hist2<<<NR * SLICES, 512, 0, stream>>>(src, dst, pSrc, pDst);
    k_scanprep<<<(NR * RNODES + 255) / 256, 256, 0, stream>>>(weight, sig, emb, pSrc, pDst,
                                                              icnt, oinv, iinv, feats3,
                                                              ovf_cnt, N_NODES);
    k_fill3<<<NR * SLICES, 512, 0, stream>>>(src, dst, pDst, eidx, ovf_cnt, ovf);
    k_aggl1<<<(N_NODES * 32 + 255) / 256, 256, 0, stream>>>(icnt, eidx, feats3,
                                                            ovf_cnt, ovf, iinv, oinv,
                                                            W0, b0, hs, N_NODES);
    k_gather128<<<((N_NODES * 32) + 255) / 256, 256, 0, stream>>>(icnt, eidx, hs,
                                                                  ovf_cnt, ovf, aggbuf,
                                                                  N_NODES);
    k_final<<<((N_NODES + FB_NODES - 1) / FB_NODES) * 2, 256, 0, stream>>>(
        iinv, W1, b1, aggbuf, out, N_NODES);
}

// Round 15
// 127.645 us; speedup vs baseline: 10.0702x; 1.0412x over previous
//
#include <hip/hip_runtime.h>

#define N_NODES 50000
#define N_EDGES 800000
#define DIM 128
#define NEG_SLOPE 0.01f
#define CAP 32           // bucket capacity
#define OVF_MAX 4096     // overflow list capacity (expected usage: tens)

// ---- range/slice partitioning ----
#define NR 4             // node ranges
#define RNODES 12512     // nodes per range (4*12512 = 50048 >= 50000), LDS 50 KB
#define SLICES 64        // edge slices
#define ESLICE (N_EDGES / SLICES)   // 12500 edges per slice

// ---- bf16 pack/unpack (RNE) ----
__device__ inline unsigned f2b_rne2(float a, float b) {
    unsigned ua = __float_as_uint(a), ub = __float_as_uint(b);
    ua = (ua + 0x7fffu + ((ua >> 16) & 1u)) >> 16;
    ub = (ub + 0x7fffu + ((ub >> 16) & 1u)) >> 16;
    return ua | (ub << 16);
}
__device__ inline float b2f_lo(unsigned u) { return __uint_as_float(u << 16); }
__device__ inline float b2f_hi(unsigned u) { return __uint_as_float(u & 0xffff0000u); }

// ---------------- dual histogram: src + dst per (range, slice), LDS-privatized ----------------
__global__ __launch_bounds__(512) void k_hist2(const int* __restrict__ src,
                                               const int* __restrict__ dst,
                                               int* __restrict__ pSrc, int* __restrict__ pDst) {
    __shared__ int bs[RNODES];             // 50 KB src bins
    __shared__ int bd[RNODES];             // 50 KB dst bins
    int range = blockIdx.x / SLICES;
    int slice = blockIdx.x % SLICES;
    int tid = threadIdx.x;
    for (int j = tid; j < RNODES; j += 512) { bs[j] = 0; bd[j] = 0; }
    __syncthreads();
    int base = range * RNODES;
    const int4* s4 = (const int4*)(src + slice * ESLICE);
    const int4* d4 = (const int4*)(dst + slice * ESLICE);
    for (int t = tid; t < ESLICE / 4; t += 512) {
        int4 v = s4[t];
        unsigned u0 = (unsigned)(v.x - base), u1 = (unsigned)(v.y - base);
        unsigned u2 = (unsigned)(v.z - base), u3 = (unsigned)(v.w - base);
        if (u0 < RNODES) atomicAdd(&bs[u0], 1);
        if (u1 < RNODES) atomicAdd(&bs[u1], 1);
        if (u2 < RNODES) atomicAdd(&bs[u2], 1);
        if (u3 < RNODES) atomicAdd(&bs[u3], 1);
        int4 w = d4[t];
        unsigned w0 = (unsigned)(w.x - base), w1 = (unsigned)(w.y - base);
        unsigned w2 = (unsigned)(w.z - base), w3 = (unsigned)(w.w - base);
        if (w0 < RNODES) atomicAdd(&bd[w0], 1);
        if (w1 < RNODES) atomicAdd(&bd[w1], 1);
        if (w2 < RNODES) atomicAdd(&bd[w2], 1);
        if (w3 < RNODES) atomicAdd(&bd[w3], 1);
    }
    __syncthreads();
    int* os = pSrc + (size_t)blockIdx.x * RNODES;
    int* od = pDst + (size_t)blockIdx.x * RNODES;
    for (int j = tid; j < RNODES; j += 512) { os[j] = bs[j]; od[j] = bd[j]; }
}

// ---------------- scan dst partials (in place) + fused prep + ovf_cnt reset ----------------
__global__ void k_scanprep(const float* __restrict__ weight, const int* __restrict__ sig,
                           const float* __restrict__ emb,
                           const int* __restrict__ pSrc, int* __restrict__ pDst,
                           int* __restrict__ icnt, float* __restrict__ oinv,
                           float* __restrict__ iinv, float* __restrict__ feats3,
                           int* __restrict__ ovf_cnt, int n) {
    int g = blockIdx.x * blockDim.x + threadIdx.x;
    if (g == 0) *ovf_cnt = 0;              // runs before k_fill3 on the stream
    if (g >= NR * RNODES) return;
    int range = g / RNODES, off = g % RNODES;
    size_t basei = (size_t)(range * SLICES) * RNODES + off;
    int run = 0;
    #pragma unroll 8
    for (int s = 0; s < SLICES; ++s) {
        size_t idx = basei + (size_t)s * RNODES;
        int c = pDst[idx];
        pDst[idx] = run;                   // exclusive prefix for slice s
        run += c;
    }
    int od = 0;
    #pragma unroll 8
    for (int s = 0; s < SLICES; ++s) od += pSrc[basei + (size_t)s * RNODES];
    if (g < n) {
        icnt[g] = run;                     // total in-degree
        float oi = 1.0f / sqrtf((float)max(od, 1));
        oinv[g] = oi;
        iinv[g] = 1.0f / sqrtf((float)max(run, 1));
        int sg = sig[g];
        feats3[g * 3 + 0] = weight[g] * oi;
        feats3[g * 3 + 1] = emb[sg * 2 + 0] * oi;
        feats3[g * 3 + 2] = emb[sg * 2 + 1] * oi;
    }
}

// ---------------- atomic-free bucket fill: LDS prefix-cursors ----------------
__global__ __launch_bounds__(512) void k_fill3(const int* __restrict__ src,
                                               const int* __restrict__ dst,
                                               const int* __restrict__ pDst,
                                               unsigned short* __restrict__ eidx,
                                               int* __restrict__ ovf_cnt, int2* __restrict__ ovf) {
    __shared__ int cur[RNODES];            // 50 KB prefix-initialized cursors
    int range = blockIdx.x / SLICES;
    int slice = blockIdx.x % SLICES;
    int tid = threadIdx.x;
    const int* pr = pDst + (size_t)blockIdx.x * RNODES;
    for (int j = tid; j < RNODES; j += 512) cur[j] = pr[j];
    __syncthreads();
    int base = range * RNODES;
    const int* ss = src + slice * ESLICE;
    const int* dd = dst + slice * ESLICE;
    for (int t = tid; t < ESLICE; t += 512) {
        int d = dd[t];
        unsigned u = (unsigned)(d - base);
        if (u < RNODES) {
            int s = ss[t];
            int p = atomicAdd(&cur[u], 1);
            if (p < CAP) eidx[(size_t)d * CAP + p] = (unsigned short)s;
            else { int o = atomicAdd(ovf_cnt, 1); if (o < OVF_MAX) ovf[o] = make_int2(d, s); }
        }
    }
}

// ---------------- fused layer-1: gather + ovf-fold + (.@W0+b0) + lrelu + bf16 pack ----------------
__global__ void k_aggl1(const int* __restrict__ icnt, const unsigned short* __restrict__ eidx,
                        const float* __restrict__ feats3,
                        const int* __restrict__ ovf_cnt, const int2* __restrict__ ovf,
                        const float* __restrict__ iinv, const float* __restrict__ oinv,
                        const float* __restrict__ W0, const float* __restrict__ b0,
                        unsigned* __restrict__ hs, int n) {
    int t = blockIdx.x * blockDim.x + threadIdx.x;
    int i = t >> 5;
    if (i >= n) return;
    int q = t & 31;
    int ic = icnt[i];
    int deg = min(ic, CAP);
    const unsigned short* row = eidx + (size_t)i * CAP;
    float a0 = 0.f, a1 = 0.f, a2 = 0.f;
    for (int k = q; k < deg; k += 32) {
        int s = row[k];
        a0 += feats3[s * 3 + 0];
        a1 += feats3[s * 3 + 1];
        a2 += feats3[s * 3 + 2];
    }
    if (ic > CAP) {                        // rare (~6 nodes): fold overflow edges
        int cnt = min(*ovf_cnt, OVF_MAX);
        for (int e = q; e < cnt; e += 32) {
            int2 ov = ovf[e];              // (dst, src)
            if (ov.x == i) {
                a0 += feats3[ov.y * 3 + 0];
                a1 += feats3[ov.y * 3 + 1];
                a2 += feats3[ov.y * 3 + 2];
            }
        }
    }
    #pragma unroll
    for (int m = 1; m <= 16; m <<= 1) {
        a0 += __shfl_xor(a0, m);
        a1 += __shfl_xor(a1, m);
        a2 += __shfl_xor(a2, m);
    }
    float ii = iinv[i], oi = oinv[i];
    a0 *= ii; a1 *= ii; a2 *= ii;
    int j0 = q * 4;
    float4 w0r = *(const float4*)&W0[0 * DIM + j0];
    float4 w1r = *(const float4*)&W0[1 * DIM + j0];
    float4 w2r = *(const float4*)&W0[2 * DIM + j0];
    float4 bb  = *(const float4*)&b0[j0];
    float v0 = a0 * w0r.x + a1 * w1r.x + a2 * w2r.x + bb.x;
    float v1 = a0 * w0r.y + a1 * w1r.y + a2 * w2r.y + bb.y;
    float v2 = a0 * w0r.z + a1 * w1r.z + a2 * w2r.z + bb.z;
    float v3 = a0 * w0r.w + a1 * w1r.w + a2 * w2r.w + bb.w;
    v0 = v0 > 0.f ? v0 : NEG_SLOPE * v0;
    v1 = v1 > 0.f ? v1 : NEG_SLOPE * v1;
    v2 = v2 > 0.f ? v2 : NEG_SLOPE * v2;
    v3 = v3 > 0.f ? v3 : NEG_SLOPE * v3;
    ((uint2*)hs)[i * 32 + q] = make_uint2(f2b_rne2(v0 * oi, v1 * oi),
                                          f2b_rne2(v2 * oi, v3 * oi));
}

// ---------------- layer-2 aggregation: bucket gather (8-deep MLP) -> aggbuf ----------------
// eidx->hs is a dependent-load chain; group 8 edges: 8 broadcast ushort reads
// (L1-hit, same 64B line) then 8 INDEPENDENT 256B row fetches in flight.
__global__ void k_gather128(const int* __restrict__ icnt, const unsigned short* __restrict__ eidx,
                            const unsigned* __restrict__ hs,
                            const int* __restrict__ ovf_cnt, const int2* __restrict__ ovf,
                            float* __restrict__ agg, int n) {
    int t = blockIdx.x * blockDim.x + threadIdx.x;
    int i = t >> 5;
    if (i >= n) return;
    int q = t & 31;
    int ic = icnt[i];
    int deg = min(ic, CAP);
    const unsigned short* row = eidx + (size_t)i * CAP;
    const uint2* hs2 = (const uint2*)hs;
    float a0 = 0.f, a1 = 0.f, a2 = 0.f, a3 = 0.f;
    int k = 0;
    for (; k + 8 <= deg; k += 8) {
        int s0 = row[k + 0], s1 = row[k + 1], s2 = row[k + 2], s3 = row[k + 3];
        int s4 = row[k + 4], s5 = row[k + 5], s6 = row[k + 6], s7 = row[k + 7];
        uint2 u0 = hs2[s0 * 32 + q];
        uint2 u1 = hs2[s1 * 32 + q];
        uint2 u2 = hs2[s2 * 32 + q];
        uint2 u3 = hs2[s3 * 32 + q];
        uint2 u4 = hs2[s4 * 32 + q];
        uint2 u5 = hs2[s5 * 32 + q];
        uint2 u6 = hs2[s6 * 32 + q];
        uint2 u7 = hs2[s7 * 32 + q];
        a0 += (b2f_lo(u0.x) + b2f_lo(u1.x)) + (b2f_lo(u2.x) + b2f_lo(u3.x))
            + (b2f_lo(u4.x) + b2f_lo(u5.x)) + (b2f_lo(u6.x) + b2f_lo(u7.x));
        a1 += (b2f_hi(u0.x) + b2f_hi(u1.x)) + (b2f_hi(u2.x) + b2f_hi(u3.x))
            + (b2f_hi(u4.x) + b2f_hi(u5.x)) + (b2f_hi(u6.x) + b2f_hi(u7.x));
        a2 += (b2f_lo(u0.y) + b2f_lo(u1.y)) + (b2f_lo(u2.y) + b2f_lo(u3.y))
            + (b2f_lo(u4.y) + b2f_lo(u5.y)) + (b2f_lo(u6.y) + b2f_lo(u7.y));
        a3 += (b2f_hi(u0.y) + b2f_hi(u1.y)) + (b2f_hi(u2.y) + b2f_hi(u3.y))
            + (b2f_hi(u4.y) + b2f_hi(u5.y)) + (b2f_hi(u6.y) + b2f_hi(u7.y));
    }
    for (; k + 2 <= deg; k += 2) {
        int s0 = row[k], s1 = row[k + 1];
        uint2 u0 = hs2[s0 * 32 + q];
        uint2 u1 = hs2[s1 * 32 + q];
        a0 += b2f_lo(u0.x) + b2f_lo(u1.x);
        a1 += b2f_hi(u0.x) + b2f_hi(u1.x);
        a2 += b2f_lo(u0.y) + b2f_lo(u1.y);
        a3 += b2f_hi(u0.y) + b2f_hi(u1.y);
    }
    if (k < deg) {
        int s = row[k];
        uint2 u = hs2[s * 32 + q];
        a0 += b2f_lo(u.x); a1 += b2f_hi(u.x);
        a2 += b2f_lo(u.y); a3 += b2f_hi(u.y);
    }
    if (ic > CAP) {                        // rare: fold overflow edges
        int cnt = min(*ovf_cnt, OVF_MAX);
        for (int e = 0; e < cnt; ++e) {
            int2 ov = ovf[e];              // (dst, src)
            if (ov.x == i) {
                uint2 u = hs2[ov.y * 32 + q];
                a0 += b2f_lo(u.x); a1 += b2f_hi(u.x);
                a2 += b2f_lo(u.y); a3 += b2f_hi(u.y);
            }
        }
    }
    ((float4*)agg)[i * 32 + q] = make_float4(a0, a1, a2, a3);
}

// ---------------- final: out = (agg * iinv) @ W1 + b1, column-split ----------------
#define FB_NODES 256
__global__ __launch_bounds__(256) void k_final(const float* __restrict__ iinv,
                                               const float* __restrict__ W1,
                                               const float* __restrict__ b1,
                                               const float* __restrict__ agg,
                                               float* __restrict__ out, int n) {
    __shared__ float sW[DIM * 64];         // 32 KB: W1[:, half*64 .. half*64+63]
    int tid = threadIdx.x;
    int half = blockIdx.x & 1;
    int tile = blockIdx.x >> 1;
    for (int idx = tid; idx < DIM * 64 / 4; idx += 256) {
        int r = idx >> 4, c4 = idx & 15;
        *(float4*)&sW[r * 64 + c4 * 4] = *(const float4*)&W1[r * DIM + half * 64 + c4 * 4];
    }
    int cg = tid & 7;                      // 8 col-groups of 8 cols
    int ng = tid >> 3;                     // 32 row-groups of 8 rows
    int col0 = cg * 8;
    int row0 = tile * FB_NODES + ng * 8;

    float acc[8][8];
    #pragma unroll
    for (int i = 0; i < 8; ++i)
        #pragma unroll
        for (int j = 0; j < 8; ++j) acc[i][j] = 0.f;

    __syncthreads();

    const float4* agg4 = (const float4*)agg;
    for (int k4 = 0; k4 < 32; ++k4) {
        float4 a[8];
        #pragma unroll
        for (int i = 0; i < 8; ++i) {
            int r = min(row0 + i, n - 1);          // clamped read; store is guarded
            a[i] = agg4[(size_t)r * 32 + k4];
        }
        #pragma unroll
        for (int kk = 0; kk < 4; ++kk) {
            float4 w0 = *(const float4*)&sW[(k4 * 4 + kk) * 64 + col0];
            float4 w1v = *(const float4*)&sW[(k4 * 4 + kk) * 64 + col0 + 4];
            #pragma unroll
            for (int i = 0; i < 8; ++i) {
                float av = (kk == 0) ? a[i].x : (kk == 1) ? a[i].y : (kk == 2) ? a[i].z : a[i].w;
                acc[i][0] += av * w0.x;  acc[i][1] += av * w0.y;
                acc[i][2] += av * w0.z;  acc[i][3] += av * w0.w;
                acc[i][4] += av * w1v.x; acc[i][5] += av * w1v.y;
                acc[i][6] += av * w1v.z; acc[i][7] += av * w1v.w;
            }
        }
    }

    int gcol = half * 64 + col0;
    float4 bb0 = *(const float4*)&b1[gcol];
    float4 bb1 = *(const float4*)&b1[gcol + 4];
    #pragma unroll
    for (int i = 0; i < 8; ++i) {
        int r = row0 + i;
        if (r < n) {
            float ii = iinv[r];
            float4 o0, o1;
            o0.x = acc[i][0] * ii + bb0.x; o0.y = acc[i][1] * ii + bb0.y;
            o0.z = acc[i][2] * ii + bb0.z; o0.w = acc[i][3] * ii + bb0.w;
            o1.x = acc[i][4] * ii + bb1.x; o1.y = acc[i][5] * ii + bb1.y;
            o1.z = acc[i][6] * ii + bb1.z; o1.w = acc[i][7] * ii + bb1.w;
            ((float4*)out)[(size_t)r * 32 + (gcol >> 2)] = o0;
            ((float4*)out)[(size_t)r * 32 + (gcol >> 2) + 1] = o1;
        }
    }
}

// ---------------- launch ----------------
extern "C" void kernel_launch(void* const* d_in, const int* in_sizes, int n_in,
                              void* d_out, int out_size, void* d_ws, size_t ws_size,
                              hipStream_t stream) {
    const int*   src  = (const int*)d_in[0];
    const int*   dst  = (const int*)d_in[1];
    const float* weight = (const float*)d_in[2];
    const int*   sig  = (const int*)d_in[3];
    const float* emb  = (const float*)d_in[4];
    const float* W0   = (const float*)d_in[5];
    const float* b0   = (const float*)d_in[6];
    const float* W1   = (const float*)d_in[7];
    const float* b1   = (const float*)d_in[8];
    float* out = (float*)d_out;

    // ---- workspace layout (4B words); no memsets needed ----
    int*   ovf_cnt = (int*)d_ws;                          // @0        8 (zeroed by k_scanprep)
    int2*  ovf     = (int2*)(ovf_cnt + 8);                // @8        4096 int2 (byte %8==0)
    int*   icnt    = (int*)(ovf + OVF_MAX);               // @8200     50000
    float* oinv    = (float*)(icnt + N_NODES);            // @58200    50000
    float* iinv    = oinv + N_NODES;                      // @108200   50000
    float* feats3  = iinv + N_NODES;                      // @158200   150000
    int*   pSrc    = (int*)(feats3 + 3 * N_NODES);        // @308200   3,203,072
    int*   pDst    = pSrc + (size_t)NR * SLICES * RNODES;
    unsigned short* eidx = (unsigned short*)(pDst + (size_t)NR * SLICES * RNODES);
    unsigned* hs   = (unsigned*)(eidx + (size_t)N_NODES * CAP);     // 3.2M words
    float* aggbuf  = (float*)(hs + (size_t)N_NODES * 64);           // 6.4M words

    k_hist2<<<NR * SLICES, 512, 0, stream>>>(src, dst, pSrc, pDst);
    k_scanprep<<<(NR * RNODES + 255) / 256, 256, 0, stream>>>(weight, sig, emb, pSrc, pDst,
                                                              icnt, oinv, iinv, feats3,
                                                              ovf_cnt, N_NODES);
    k_fill3<<<NR * SLICES, 512, 0, stream>>>(src, dst, pDst, eidx, ovf_cnt, ovf);
    k_aggl1<<<(N_NODES * 32 + 255) / 256, 256, 0, stream>>>(icnt, eidx, feats3,
                                                            ovf_cnt, ovf, iinv, oinv,
                                                            W0, b0, hs, N_NODES);
    k_gather128<<<((N_NODES * 32) + 255) / 256, 256, 0, stream>>>(icnt, eidx, hs,
                                                                  ovf_cnt, ovf, aggbuf,
                                                                  N_NODES);
    k_final<<<((N_NODES + FB_NODES - 1) / FB_NODES) * 2, 256, 0, stream>>>(
        iinv, W1, b1, aggbuf, out, N_NODES);
}